// Round 6
// baseline (370.243 us; speedup 1.0000x reference)
//
#include <hip/hip_runtime.h>
#include <hip/hip_bf16.h>
#include <math.h>

#define B 64
#define S 2048
#define H 512
#define BM 32
#define NBLK 256

// workspace layout (floats)
#define QS_OFF 0                    // qs:     B*H
#define SC_OFF (B*H)                // scores: B*S
#define PC_OFF (B*H + B*S)          // pc:     B*NCHUNK*H  (Wt aliases this region, used before pc)
#define NCHUNK 32
#define CHUNK  64                   // S / NCHUNK

typedef __attribute__((ext_vector_type(8))) short short8;
typedef __attribute__((ext_vector_type(4))) float f32x4;

static __device__ __forceinline__ short f2bf(float f) {
    union { float f; unsigned u; } x; x.f = f;
    unsigned r = x.u + 0x7fffu + ((x.u >> 16) & 1u);   // RNE
    return (short)(r >> 16);
}

static __device__ __forceinline__ float ftanh(float x) {
    x = fminf(fmaxf(x, -30.f), 30.f);
    const float e = __builtin_amdgcn_exp2f(x * 2.8853900817779268f); // e^(2x)
    return (e - 1.f) * __builtin_amdgcn_rcpf(e + 1.f);
}

static __device__ __forceinline__ short8 cvt8(float4 a, float4 b) {
    union { short8 s; __hip_bfloat162 h[4]; } u;
    u.h[0] = __float22bfloat162_rn(make_float2(a.x, a.y));
    u.h[1] = __float22bfloat162_rn(make_float2(a.z, a.w));
    u.h[2] = __float22bfloat162_rn(make_float2(b.x, b.y));
    u.h[3] = __float22bfloat162_rn(make_float2(b.z, b.w));
    return u.s;
}

// ---------------- kernel 1: q_scores = query @ W_s (B,H) ----------------
__global__ __launch_bounds__(512) void qs_kernel(const float* __restrict__ query,
                                                 const float* __restrict__ W_s,
                                                 float* __restrict__ qs) {
    const int b = blockIdx.x, k = threadIdx.x;
    __shared__ float q[H];
    q[k] = query[b * H + k];
    __syncthreads();
    float acc = 0.f;
#pragma unroll 8
    for (int h = 0; h < H; ++h) acc = fmaf(q[h], W_s[h * H + k], acc);
    qs[b * H + k] = acc;
}

// -------- kernel 1b: W_h -> bf16 fragment-ordered Wt --------
// layout offset(st,w,cb,l,j) = st*16384 + w*2048 + cb*512 + l*8 + j
// element = W_h[k][col], k = st*32 + (l>>4)*8 + j, col = w*64 + cb*16 + (l&15)
__global__ __launch_bounds__(256) void wt_prep(const float* __restrict__ W_h,
                                               short* __restrict__ Wt) {
    const int idx = blockIdx.x * 256 + threadIdx.x;       // 0 .. 262143
    const int j  = idx & 7;
    const int l  = (idx >> 3) & 63;
    const int cb = (idx >> 9) & 3;
    const int w  = (idx >> 11) & 7;
    const int st = idx >> 14;
    const int k   = st * 32 + (l >> 4) * 8 + j;
    const int col = w * 64 + cb * 16 + (l & 15);
    Wt[idx] = f2bf(W_h[k * H + col]);
}

// ------- kernel 2: scores = v . tanh(enc @ W_h + qs) — persistent B-in-regs -------
// 256 blocks x 512 thr (8 waves x 64 cols). Each block: load its Wt slab to regs
// ONCE, then loop over ~8 alive 32-row tiles with zero loads in the k-loop.
// __launch_bounds__(512, 2): 2 waves/SIMD -> 256-reg cap, room for Breg[16][4].
__global__ __launch_bounds__(512, 2) void scores_mfma_kernel(const float* __restrict__ enc,
                                                             const short* __restrict__ Wt,
                                                             const float* __restrict__ v,
                                                             const int* __restrict__ lens,
                                                             const float* __restrict__ qs,
                                                             float* __restrict__ scores) {
    const int t = threadIdx.x;
    const int w = t >> 6, l = t & 63;
    const int g = l >> 4, c = l & 15;

    __shared__ char Abuf[2][32768];     // double-buffered 32x512 bf16 tile (swizzled)
    __shared__ float red[8][BM];
    __shared__ int bl[16], sl[16], s_na;

    // ---- alive-slot scan (staggered for balance) ----
    if (t == 0) {
        int n = 0;
        for (int k = 0; k < 16; ++k) {
            const int slot = blockIdx.x + NBLK * k;
            const int b_ = slot >> 6;
            const int tt = ((slot & 63) + b_) & 63;
            const int s0_ = tt * BM;
            if (s0_ < lens[b_]) { bl[n] = b_; sl[n] = s0_; ++n; }
        }
        s_na = n;
    }
    __syncthreads();
    const int na = s_na;
    if (na == 0) return;

    // ---- persistent B fragments: 16 steps x 4 col-blocks, 128 VGPRs ----
    short8 Breg[16][4];
    {
        const short* wb = Wt + w * 2048 + (size_t)l * 8;
#pragma unroll
        for (int st = 0; st < 16; ++st)
#pragma unroll
            for (int cb = 0; cb < 4; ++cb)
                Breg[st][cb] = *(const short8*)(wb + st * 16384 + cb * 512);
    }

    // v preload (cols fixed per lane across slots)
    float vreg[4];
#pragma unroll
    for (int cb = 0; cb < 4; ++cb) vreg[cb] = v[w * 64 + cb * 16 + c];

    // staging geometry: row = t&31, 32 contiguous floats at (t>>5)*32
    const int srow = t & 31;
    const int scol = (t >> 5) * 32;
    const int swr  = ((srow & 7) << 4) ^ (((srow >> 3) & 3) << 8);
    // A-frag read swizzles
    const int sw0 = ((c & 7) << 4) ^ (((c >> 3) & 3) << 8);
    const int sw1 = sw0 ^ 0x200;

#define STAGEREG(b_, s0_)                                                      \
    {                                                                          \
        const float4* ap_ = (const float4*)(enc + ((size_t)((b_) * S + (s0_) + srow)) * H + scol); \
        AF0 = ap_[0]; AF1 = ap_[1]; AF2 = ap_[2]; AF3 = ap_[3];                \
        AF4 = ap_[4]; AF5 = ap_[5]; AF6 = ap_[6]; AF7 = ap_[7];                \
    }

    float4 AF0, AF1, AF2, AF3, AF4, AF5, AF6, AF7;
    STAGEREG(bl[0], sl[0])

    for (int i = 0; i < na; ++i) {
        const int b  = bl[i];
        const int s0 = sl[i];
        char* Ab = Abuf[i & 1];

        // qs prefetch (issue early)
        float qreg[4];
#pragma unroll
        for (int cb = 0; cb < 4; ++cb) qreg[cb] = qs[b * H + w * 64 + cb * 16 + c];

        // cvt + swizzled ds_write of tile i
        {
            char* wp = Ab + srow * 1024;
            *(short8*)(wp + ((scol * 2 +  0) ^ swr)) = cvt8(AF0, AF1);
            *(short8*)(wp + ((scol * 2 + 16) ^ swr)) = cvt8(AF2, AF3);
            *(short8*)(wp + ((scol * 2 + 32) ^ swr)) = cvt8(AF4, AF5);
            *(short8*)(wp + ((scol * 2 + 48) ^ swr)) = cvt8(AF6, AF7);
        }
        __syncthreads();

        // issue next tile's global loads early (T14) — covered by MFMA phase
        if (i + 1 < na) STAGEREG(bl[i + 1], sl[i + 1])

        f32x4 acc[2][4];
        const f32x4 z = {0.f, 0.f, 0.f, 0.f};
#pragma unroll
        for (int rb = 0; rb < 2; ++rb)
#pragma unroll
            for (int cb = 0; cb < 4; ++cb) acc[rb][cb] = z;

        const char* a0p = Ab + c * 1024;
        const char* a1p = Ab + (16 + c) * 1024;
#pragma unroll
        for (int st = 0; st < 16; ++st) {
            const int koff = st * 64 + g * 16;
            const short8 a0 = *(const short8*)(a0p + (koff ^ sw0));
            const short8 a1 = *(const short8*)(a1p + (koff ^ sw1));
#pragma unroll
            for (int cb = 0; cb < 4; ++cb) {
                acc[0][cb] = __builtin_amdgcn_mfma_f32_16x16x32_bf16(a0, Breg[st][cb], acc[0][cb], 0, 0, 0);
                acc[1][cb] = __builtin_amdgcn_mfma_f32_16x16x32_bf16(a1, Breg[st][cb], acc[1][cb], 0, 0, 0);
            }
        }

        // epilogue: p[row] = sum_col v[col] * tanh(escore + qs[col])
        float part[2][4];
#pragma unroll
        for (int rb = 0; rb < 2; ++rb)
#pragma unroll
            for (int r = 0; r < 4; ++r) part[rb][r] = 0.f;
#pragma unroll
        for (int cb = 0; cb < 4; ++cb)
#pragma unroll
            for (int rb = 0; rb < 2; ++rb)
#pragma unroll
                for (int r = 0; r < 4; ++r)
                    part[rb][r] += vreg[cb] * ftanh(acc[rb][cb][r] + qreg[cb]);
#pragma unroll
        for (int m = 1; m < 16; m <<= 1)
#pragma unroll
            for (int rb = 0; rb < 2; ++rb)
#pragma unroll
                for (int r = 0; r < 4; ++r)
                    part[rb][r] += __shfl_xor(part[rb][r], m);
        if (c == 0) {
#pragma unroll
            for (int rb = 0; rb < 2; ++rb)
#pragma unroll
                for (int r = 0; r < 4; ++r)
                    red[w][rb * 16 + g * 4 + r] = part[rb][r];
        }
        __syncthreads();
        if (t < BM) {
            float sc = red[0][t] + red[1][t] + red[2][t] + red[3][t] +
                       red[4][t] + red[5][t] + red[6][t] + red[7][t];
            scores[b * S + s0 + t] = sc;
        }
    }
#undef STAGEREG
}

// ---------------- kernel 3: masked softmax over S, write attn ----------------
__global__ __launch_bounds__(256) void softmax_kernel(const float* __restrict__ scores,
                                                      const int* __restrict__ lens,
                                                      float* __restrict__ attn) {
    const int b = blockIdx.x, t = threadIdx.x;
    const int len = lens[b];
    const int wave = t >> 6, lane = t & 63;
    __shared__ float red[4];

    float vals[8];
    float m = -INFINITY;
#pragma unroll
    for (int i = 0; i < 8; ++i) {
        const int s = i * 256 + t;
        vals[i] = (s < len) ? scores[b * S + s] : -INFINITY;
        m = fmaxf(m, vals[i]);
    }
#pragma unroll
    for (int off = 32; off > 0; off >>= 1) m = fmaxf(m, __shfl_down(m, off));
    if (lane == 0) red[wave] = m;
    __syncthreads();
    m = fmaxf(fmaxf(red[0], red[1]), fmaxf(red[2], red[3]));
    __syncthreads();

    float e[8];
    float sum = 0.f;
#pragma unroll
    for (int i = 0; i < 8; ++i) {
        const int s = i * 256 + t;
        e[i] = (s < len) ? expf(vals[i] - m) : 0.f;
        sum += e[i];
    }
#pragma unroll
    for (int off = 32; off > 0; off >>= 1) sum += __shfl_down(sum, off);
    if (lane == 0) red[wave] = sum;
    __syncthreads();
    const float inv = 1.f / (red[0] + red[1] + red[2] + red[3]);
#pragma unroll
    for (int i = 0; i < 8; ++i) attn[b * S + i * 256 + t] = e[i] * inv;
}

// -------- kernel 4a: partial context sums over s-chunks (masked skipped) --------
__global__ __launch_bounds__(256) void ctx_partial_kernel(const float* __restrict__ enc,
                                                          const float* __restrict__ attn,
                                                          const int* __restrict__ lens,
                                                          float* __restrict__ pc) {
    const int b = blockIdx.x >> 5, c = blockIdx.x & 31;
    const int len = lens[b];
    const int sbase = c * CHUNK;
    if (sbase >= len) return;
    const int ns = min(CHUNK, len - sbase);
    const int t = threadIdx.x;

    __shared__ float alds[CHUNK];
    if (t < CHUNK) alds[t] = (t < ns) ? attn[b * S + sbase + t] : 0.f;
    __syncthreads();

    const float2* e2 = (const float2*)(enc + (size_t)(b * S + sbase) * H);
    float2 acc = make_float2(0.f, 0.f);
    for (int s = 0; s < ns; ++s) {
        const float a = alds[s];
        const float2 e = e2[s * 256 + t];
        acc.x = fmaf(a, e.x, acc.x);
        acc.y = fmaf(a, e.y, acc.y);
    }
    ((float2*)(pc + (size_t)(b * NCHUNK + c) * H))[t] = acc;
}

// ------ kernel 4b: context reduce + w_out = tanh([ctx, q] @ W_out) ------
__global__ __launch_bounds__(512) void out_kernel(const float* __restrict__ pc,
                                                  const float* __restrict__ query,
                                                  const float* __restrict__ W_out,
                                                  const int* __restrict__ lens,
                                                  float* __restrict__ wout) {
    const int b = blockIdx.x, k = threadIdx.x;
    const int len = lens[b];
    const int nch = (len + CHUNK - 1) / CHUNK;
    __shared__ float cat[2 * H];
    float ctx = 0.f;
    for (int c = 0; c < nch; ++c) ctx += pc[(size_t)(b * NCHUNK + c) * H + k];
    cat[k] = ctx;
    cat[H + k] = query[b * H + k];
    __syncthreads();
    float acc = 0.f;
#pragma unroll 8
    for (int c = 0; c < 2 * H; ++c) acc = fmaf(cat[c], W_out[c * H + k], acc);
    wout[b * H + k] = tanhf(acc);
}

extern "C" void kernel_launch(void* const* d_in, const int* in_sizes, int n_in,
                              void* d_out, int out_size, void* d_ws, size_t ws_size,
                              hipStream_t stream) {
    const float* query = (const float*)d_in[0];
    const float* enc   = (const float*)d_in[1];
    const int*   lens  = (const int*)d_in[2];
    const float* W_h   = (const float*)d_in[3];
    const float* W_s   = (const float*)d_in[4];
    const float* v     = (const float*)d_in[5];
    const float* W_out = (const float*)d_in[6];

    float* out  = (float*)d_out;
    float* wout = out;          // B*H
    float* attn = out + B * H;  // B*S

    float* ws     = (float*)d_ws;
    float* qs     = ws + QS_OFF;
    float* scores = ws + SC_OFF;
    float* pc     = ws + PC_OFF;
    short* Wt     = (short*)(ws + PC_OFF);   // aliases pc: Wt used in scores (before pc written)

    qs_kernel<<<B, H, 0, stream>>>(query, W_s, qs);
    wt_prep<<<1024, 256, 0, stream>>>(W_h, Wt);
    scores_mfma_kernel<<<NBLK, 512, 0, stream>>>(enc, Wt, v, lens, qs, scores);
    softmax_kernel<<<B, 256, 0, stream>>>(scores, lens, attn);
    ctx_partial_kernel<<<B * NCHUNK, 256, 0, stream>>>(enc, attn, lens, pc);
    out_kernel<<<B, H, 0, stream>>>(pc, query, W_out, lens, wout);
}

// Round 7
// 202.493 us; speedup vs baseline: 1.8284x; 1.8284x over previous
//
#include <hip/hip_runtime.h>
#include <hip/hip_bf16.h>
#include <math.h>

#define B 64
#define S 2048
#define H 512
#define BMT 64

// workspace layout (floats)
#define QS_OFF 0                    // qs:     B*H
#define SC_OFF (B*H)                // scores: B*S
#define PC_OFF (B*H + B*S)          // pc:     B*NCHUNK*H  (Wt aliases this region, used before pc)
#define NCHUNK 32
#define CHUNK  64                   // S / NCHUNK

typedef __attribute__((ext_vector_type(8))) short short8;
typedef __attribute__((ext_vector_type(4))) float f32x4;

static __device__ __forceinline__ short f2bf(float f) {
    union { float f; unsigned u; } x; x.f = f;
    unsigned r = x.u + 0x7fffu + ((x.u >> 16) & 1u);   // RNE
    return (short)(r >> 16);
}

static __device__ __forceinline__ float ftanh(float x) {
    x = fminf(fmaxf(x, -30.f), 30.f);
    const float e = __builtin_amdgcn_exp2f(x * 2.8853900817779268f); // e^(2x)
    return (e - 1.f) * __builtin_amdgcn_rcpf(e + 1.f);
}

static __device__ __forceinline__ short8 cvt8(float4 a, float4 b) {
    union { short8 s; __hip_bfloat162 h[4]; } u;
    u.h[0] = __float22bfloat162_rn(make_float2(a.x, a.y));
    u.h[1] = __float22bfloat162_rn(make_float2(a.z, a.w));
    u.h[2] = __float22bfloat162_rn(make_float2(b.x, b.y));
    u.h[3] = __float22bfloat162_rn(make_float2(b.z, b.w));
    return u.s;
}

#define GLL16(g_, l_) __builtin_amdgcn_global_load_lds(                        \
    (const __attribute__((address_space(1))) void*)(g_),                      \
    (__attribute__((address_space(3))) void*)(l_), 16, 0, 0)

// ---------------- kernel 1: q_scores = query @ W_s (B,H) ----------------
__global__ __launch_bounds__(512) void qs_kernel(const float* __restrict__ query,
                                                 const float* __restrict__ W_s,
                                                 float* __restrict__ qs) {
    const int b = blockIdx.x, k = threadIdx.x;
    __shared__ float q[H];
    q[k] = query[b * H + k];
    __syncthreads();
    float acc = 0.f;
#pragma unroll 8
    for (int h = 0; h < H; ++h) acc = fmaf(q[h], W_s[h * H + k], acc);
    qs[b * H + k] = acc;
}

// -------- kernel 1b: W_h -> bf16 step-major fragment-ordered Wt --------
// layout: [step 16][wc 4][cb 8][lane 64][j 8] shorts
// element = W_h[k][col], k = step*32 + (lane>>4)*8 + j, col = wc*128 + cb*16 + (lane&15)
__global__ __launch_bounds__(256) void wt_prep(const float* __restrict__ W_h,
                                               short* __restrict__ Wt) {
    const int idx = blockIdx.x * 256 + threadIdx.x;       // 0 .. 262143
    const int j  = idx & 7;
    const int l  = (idx >> 3) & 63;
    const int cb = (idx >> 9) & 7;
    const int wc = (idx >> 12) & 3;
    const int st = idx >> 14;
    const int k   = st * 32 + (l >> 4) * 8 + j;
    const int col = wc * 128 + cb * 16 + (l & 15);
    Wt[idx] = f2bf(W_h[k * H + col]);
}

// ------- kernel 2: scores = v . tanh(enc @ W_h + qs) — 2-phase, BK=32, full-N tile -------
// 2048 blocks (64 b x 32 row-tiles), 256 thr = 4 waves; wave w owns cols [w*128, w*128+128).
// B: global_load_lds from frag-ordered Wt (linear). A: reg-staged fp32->bf16, padded rows.
__global__ __launch_bounds__(256, 2) void scores_mfma_kernel(const float* __restrict__ enc,
                                                             const short* __restrict__ Wt,
                                                             const float* __restrict__ v,
                                                             const int* __restrict__ lens,
                                                             const float* __restrict__ qs,
                                                             float* __restrict__ scores) {
    const int b  = blockIdx.x >> 5;
    const int s0 = (blockIdx.x & 31) * BMT;
    const int len = lens[b];
    if (s0 >= len) return;

    const int t = threadIdx.x;
    const int w = t >> 6, l = t & 63;
    const int g = l >> 4, c = l & 15;

    __shared__ __attribute__((aligned(16))) char  Bs[2][32768];  // B slab: 32 K x 512 cols bf16
    __shared__ __attribute__((aligned(16))) short As[2][64 * 40]; // A tile: 64 rows x 32 k, row stride 80 B
    __shared__ float red[4][BMT];

    // A staging geometry: thread t -> row t>>2, k-slot t&3 (8 floats = 32 B)
    const int arow = t >> 2, aslot = t & 3;
    const float* agbase = enc + ((size_t)(b * S + s0 + arow)) * H + aslot * 8;
    const char* WtB = (const char*)Wt;

    float4 AF0, AF1;

#define STAGE_B(st_, pb_)                                                      \
    {                                                                          \
        const char* gs_ = WtB + (size_t)(st_) * 32768 + w * 8192 + (size_t)l * 16; \
        char* ls_ = (char*)&Bs[(pb_)][w * 8192];                               \
        GLL16(gs_,        ls_);                                                \
        GLL16(gs_ + 1024, ls_ + 1024);                                         \
        GLL16(gs_ + 2048, ls_ + 2048);                                         \
        GLL16(gs_ + 3072, ls_ + 3072);                                         \
        GLL16(gs_ + 4096, ls_ + 4096);                                         \
        GLL16(gs_ + 5120, ls_ + 5120);                                         \
        GLL16(gs_ + 6144, ls_ + 6144);                                         \
        GLL16(gs_ + 7168, ls_ + 7168);                                         \
    }

#define LOADA_G(st_)                                                           \
    {                                                                          \
        const float4* p_ = (const float4*)(agbase + (st_) * 32);               \
        AF0 = p_[0]; AF1 = p_[1];                                              \
    }

#define WRITEA(pb_)                                                            \
    *(short8*)((char*)&As[(pb_)][0] + arow * 80 + aslot * 16) = cvt8(AF0, AF1);

    f32x4 acc[4][8];
    const f32x4 z = {0.f, 0.f, 0.f, 0.f};
#pragma unroll
    for (int rb = 0; rb < 4; ++rb)
#pragma unroll
        for (int cb = 0; cb < 8; ++cb) acc[rb][cb] = z;

    float vreg[8], qreg[8];
#pragma unroll
    for (int cb = 0; cb < 8; ++cb) {
        vreg[cb] = v[w * 128 + cb * 16 + c];
        qreg[cb] = qs[b * H + w * 128 + cb * 16 + c];
    }

    // prologue: stage tile 0
    LOADA_G(0)
    STAGE_B(0, 0)
    WRITEA(0)
    __syncthreads();

    int pb = 0;
#pragma unroll
    for (int st = 0; st < 16; ++st) {
        if (st < 15) {
            LOADA_G(st + 1)          // issue early (T14) — covered by MFMA phase
            STAGE_B(st + 1, pb ^ 1)  // async GLL into other buffer
        }
        {
            const char* ab_ = (const char*)&As[pb][0] + c * 80 + g * 16;
            const char* bb_ = (const char*)&Bs[pb][w * 8192] + l * 16;
            const short8 af0 = *(const short8*)(ab_);
            const short8 af1 = *(const short8*)(ab_ + 16 * 80);
            const short8 af2 = *(const short8*)(ab_ + 32 * 80);
            const short8 af3 = *(const short8*)(ab_ + 48 * 80);
#pragma unroll
            for (int cb = 0; cb < 8; ++cb) {
                const short8 bf = *(const short8*)(bb_ + cb * 1024);
                acc[0][cb] = __builtin_amdgcn_mfma_f32_16x16x32_bf16(af0, bf, acc[0][cb], 0, 0, 0);
                acc[1][cb] = __builtin_amdgcn_mfma_f32_16x16x32_bf16(af1, bf, acc[1][cb], 0, 0, 0);
                acc[2][cb] = __builtin_amdgcn_mfma_f32_16x16x32_bf16(af2, bf, acc[2][cb], 0, 0, 0);
                acc[3][cb] = __builtin_amdgcn_mfma_f32_16x16x32_bf16(af3, bf, acc[3][cb], 0, 0, 0);
            }
        }
        if (st < 15) WRITEA(pb ^ 1)  // cvt + ds_write into other buffer
        __syncthreads();
        pb ^= 1;
    }

    // epilogue: p[row] = sum_col v[col] * tanh(escore + qs[col])
    float part[4][4];
#pragma unroll
    for (int rb = 0; rb < 4; ++rb)
#pragma unroll
        for (int r = 0; r < 4; ++r) part[rb][r] = 0.f;

#pragma unroll
    for (int cb = 0; cb < 8; ++cb)
#pragma unroll
        for (int rb = 0; rb < 4; ++rb)
#pragma unroll
            for (int r = 0; r < 4; ++r)
                part[rb][r] += vreg[cb] * ftanh(acc[rb][cb][r] + qreg[cb]);
#pragma unroll
    for (int m = 1; m < 16; m <<= 1)
#pragma unroll
        for (int rb = 0; rb < 4; ++rb)
#pragma unroll
            for (int r = 0; r < 4; ++r)
                part[rb][r] += __shfl_xor(part[rb][r], m);
    if (c == 0) {
#pragma unroll
        for (int rb = 0; rb < 4; ++rb)
#pragma unroll
            for (int r = 0; r < 4; ++r)
                red[w][rb * 16 + g * 4 + r] = part[rb][r];
    }
    __syncthreads();
    if (t < BMT)
        scores[b * S + s0 + t] = red[0][t] + red[1][t] + red[2][t] + red[3][t];
#undef STAGE_B
#undef LOADA_G
#undef WRITEA
}

// ---------------- kernel 3: masked softmax over S, write attn ----------------
__global__ __launch_bounds__(256) void softmax_kernel(const float* __restrict__ scores,
                                                      const int* __restrict__ lens,
                                                      float* __restrict__ attn) {
    const int b = blockIdx.x, t = threadIdx.x;
    const int len = lens[b];
    const int wave = t >> 6, lane = t & 63;
    __shared__ float red[4];

    float vals[8];
    float m = -INFINITY;
#pragma unroll
    for (int i = 0; i < 8; ++i) {
        const int s = i * 256 + t;
        vals[i] = (s < len) ? scores[b * S + s] : -INFINITY;
        m = fmaxf(m, vals[i]);
    }
#pragma unroll
    for (int off = 32; off > 0; off >>= 1) m = fmaxf(m, __shfl_down(m, off));
    if (lane == 0) red[wave] = m;
    __syncthreads();
    m = fmaxf(fmaxf(red[0], red[1]), fmaxf(red[2], red[3]));
    __syncthreads();

    float e[8];
    float sum = 0.f;
#pragma unroll
    for (int i = 0; i < 8; ++i) {
        const int s = i * 256 + t;
        e[i] = (s < len) ? expf(vals[i] - m) : 0.f;
        sum += e[i];
    }
#pragma unroll
    for (int off = 32; off > 0; off >>= 1) sum += __shfl_down(sum, off);
    if (lane == 0) red[wave] = sum;
    __syncthreads();
    const float inv = 1.f / (red[0] + red[1] + red[2] + red[3]);
#pragma unroll
    for (int i = 0; i < 8; ++i) attn[b * S + i * 256 + t] = e[i] * inv;
}

// -------- kernel 4a: partial context sums over s-chunks (masked skipped) --------
__global__ __launch_bounds__(256) void ctx_partial_kernel(const float* __restrict__ enc,
                                                          const float* __restrict__ attn,
                                                          const int* __restrict__ lens,
                                                          float* __restrict__ pc) {
    const int b = blockIdx.x >> 5, c = blockIdx.x & 31;
    const int len = lens[b];
    const int sbase = c * CHUNK;
    if (sbase >= len) return;
    const int ns = min(CHUNK, len - sbase);
    const int t = threadIdx.x;

    __shared__ float alds[CHUNK];
    if (t < CHUNK) alds[t] = (t < ns) ? attn[b * S + sbase + t] : 0.f;
    __syncthreads();

    const float2* e2 = (const float2*)(enc + (size_t)(b * S + sbase) * H);
    float2 acc = make_float2(0.f, 0.f);
    for (int s = 0; s < ns; ++s) {
        const float a = alds[s];
        const float2 e = e2[s * 256 + t];
        acc.x = fmaf(a, e.x, acc.x);
        acc.y = fmaf(a, e.y, acc.y);
    }
    ((float2*)(pc + (size_t)(b * NCHUNK + c) * H))[t] = acc;
}

// ------ kernel 4b: context reduce + w_out = tanh([ctx, q] @ W_out) ------
__global__ __launch_bounds__(512) void out_kernel(const float* __restrict__ pc,
                                                  const float* __restrict__ query,
                                                  const float* __restrict__ W_out,
                                                  const int* __restrict__ lens,
                                                  float* __restrict__ wout) {
    const int b = blockIdx.x, k = threadIdx.x;
    const int len = lens[b];
    const int nch = (len + CHUNK - 1) / CHUNK;
    __shared__ float cat[2 * H];
    float ctx = 0.f;
    for (int c = 0; c < nch; ++c) ctx += pc[(size_t)(b * NCHUNK + c) * H + k];
    cat[k] = ctx;
    cat[H + k] = query[b * H + k];
    __syncthreads();
    float acc = 0.f;
#pragma unroll 8
    for (int c = 0; c < 2 * H; ++c) acc = fmaf(cat[c], W_out[c * H + k], acc);
    wout[b * H + k] = tanhf(acc);
}

extern "C" void kernel_launch(void* const* d_in, const int* in_sizes, int n_in,
                              void* d_out, int out_size, void* d_ws, size_t ws_size,
                              hipStream_t stream) {
    const float* query = (const float*)d_in[0];
    const float* enc   = (const float*)d_in[1];
    const int*   lens  = (const int*)d_in[2];
    const float* W_h   = (const float*)d_in[3];
    const float* W_s   = (const float*)d_in[4];
    const float* v     = (const float*)d_in[5];
    const float* W_out = (const float*)d_in[6];

    float* out  = (float*)d_out;
    float* wout = out;          // B*H
    float* attn = out + B * H;  // B*S

    float* ws     = (float*)d_ws;
    float* qs     = ws + QS_OFF;
    float* scores = ws + SC_OFF;
    float* pc     = ws + PC_OFF;
    short* Wt     = (short*)(ws + PC_OFF);   // aliases pc: Wt used in scores (before pc written)

    qs_kernel<<<B, H, 0, stream>>>(query, W_s, qs);
    wt_prep<<<1024, 256, 0, stream>>>(W_h, Wt);
    scores_mfma_kernel<<<B * (S / BMT), 256, 0, stream>>>(enc, Wt, v, lens, qs, scores);
    softmax_kernel<<<B, 256, 0, stream>>>(scores, lens, attn);
    ctx_partial_kernel<<<B * NCHUNK, 256, 0, stream>>>(enc, attn, lens, pc);
    out_kernel<<<B, H, 0, stream>>>(pc, query, W_out, lens, wout);
}

// Round 8
// 197.966 us; speedup vs baseline: 1.8702x; 1.0229x over previous
//
#include <hip/hip_runtime.h>
#include <hip/hip_bf16.h>
#include <math.h>

#define B 64
#define S 2048
#define H 512
#define BMT 64

// workspace layout (floats)
#define QS_OFF 0                    // qs:     B*H
#define SC_OFF (B*H)                // scores: B*S
#define PC_OFF (B*H + B*S)          // pc:     B*NCHUNK*H  (Wt aliases this region, used before pc)
#define NCHUNK 32
#define CHUNK  64                   // S / NCHUNK

typedef __attribute__((ext_vector_type(8))) short short8;
typedef __attribute__((ext_vector_type(4))) short short4v;
typedef __attribute__((ext_vector_type(4))) float f32x4;

static __device__ __forceinline__ short f2bf(float f) {
    union { float f; unsigned u; } x; x.f = f;
    unsigned r = x.u + 0x7fffu + ((x.u >> 16) & 1u);   // RNE
    return (short)(r >> 16);
}

static __device__ __forceinline__ float ftanh(float x) {
    x = fminf(fmaxf(x, -30.f), 30.f);
    const float e = __builtin_amdgcn_exp2f(x * 2.8853900817779268f); // e^(2x)
    return (e - 1.f) * __builtin_amdgcn_rcpf(e + 1.f);
}

#define GLL16(g_, l_) __builtin_amdgcn_global_load_lds(                        \
    (const __attribute__((address_space(1))) void*)(g_),                      \
    (__attribute__((address_space(3))) void*)(l_), 16, 0, 0)

// ---------------- kernel 1: q_scores = query @ W_s (B,H) ----------------
__global__ __launch_bounds__(512) void qs_kernel(const float* __restrict__ query,
                                                 const float* __restrict__ W_s,
                                                 float* __restrict__ qs) {
    const int b = blockIdx.x, k = threadIdx.x;
    __shared__ float q[H];
    q[k] = query[b * H + k];
    __syncthreads();
    float acc = 0.f;
#pragma unroll 8
    for (int h = 0; h < H; ++h) acc = fmaf(q[h], W_s[h * H + k], acc);
    qs[b * H + k] = acc;
}

// -------- kernel 1b: W_h -> bf16 fragment-ordered Wt --------
// layout offset(st,w,cb,l,j) = st*16384 + w*2048 + cb*512 + l*8 + j
// element = W_h[k][col], k = st*32 + (l>>4)*8 + j, col = w*64 + cb*16 + (l&15)
__global__ __launch_bounds__(256) void wt_prep(const float* __restrict__ W_h,
                                               short* __restrict__ Wt) {
    const int idx = blockIdx.x * 256 + threadIdx.x;       // 0 .. 262143
    const int j  = idx & 7;
    const int l  = (idx >> 3) & 63;
    const int cb = (idx >> 9) & 3;
    const int w  = (idx >> 11) & 7;
    const int st = idx >> 14;
    const int k   = st * 32 + (l >> 4) * 8 + j;
    const int col = w * 64 + cb * 16 + (l & 15);
    Wt[idx] = f2bf(W_h[k * H + col]);
}

// ------- kernel 2: scores = v . tanh(enc @ W_h + qs) — 8 waves x (64x64), 2 blocks/CU -------
// 2048 blocks (64 b x 32 row-tiles), 512 thr = 8 waves; wave w owns cols [w*64, w*64+64).
// acc[4][4]=64 AGPR, peak ~110 regs/wave -> 16 waves/CU; LDS 76 KB -> 2 blocks/CU.
__global__ __launch_bounds__(512, 4) void scores_mfma_kernel(const float* __restrict__ enc,
                                                             const short* __restrict__ Wt,
                                                             const float* __restrict__ v,
                                                             const int* __restrict__ lens,
                                                             const float* __restrict__ qs,
                                                             float* __restrict__ scores) {
    const int b  = blockIdx.x >> 5;
    const int s0 = (blockIdx.x & 31) * BMT;
    const int len = lens[b];
    if (s0 >= len) return;

    const int t = threadIdx.x;
    const int w = t >> 6, l = t & 63;
    const int g = l >> 4, c = l & 15;

    __shared__ __attribute__((aligned(16))) char  Bs[2][32768];   // B slab: 32 k x 512 cols bf16
    __shared__ __attribute__((aligned(16))) short As[2][64 * 40]; // A tile: 64 rows x 32 k, row stride 80 B
    __shared__ float red[8][BMT];

    // A staging: thread t -> row t>>3, slot t&7 (4 floats = 16 B of the 128 B k-chunk)
    const int arow = t >> 3, aslot = t & 7;
    const float* agbase = enc + ((size_t)(b * S + s0 + arow)) * H + aslot * 4;
    const char* WtB = (const char*)Wt;

    float4 AF;

#define STAGE_B(st_, pb_)                                                      \
    {                                                                          \
        const char* gs_ = WtB + (size_t)(st_) * 32768 + w * 4096 + (size_t)l * 16; \
        char* ls_ = (char*)&Bs[(pb_)][w * 4096];                               \
        GLL16(gs_,        ls_);                                                \
        GLL16(gs_ + 1024, ls_ + 1024);                                         \
        GLL16(gs_ + 2048, ls_ + 2048);                                         \
        GLL16(gs_ + 3072, ls_ + 3072);                                         \
    }

#define LOADA_G(st_)  AF = *(const float4*)(agbase + (st_) * 32);

#define WRITEA(pb_)                                                            \
    {                                                                          \
        short4v h_;                                                            \
        h_[0] = f2bf(AF.x); h_[1] = f2bf(AF.y);                                \
        h_[2] = f2bf(AF.z); h_[3] = f2bf(AF.w);                                \
        *(short4v*)((char*)&As[(pb_)][0] + arow * 80 + aslot * 8) = h_;        \
    }

    f32x4 acc[4][4];
    const f32x4 z = {0.f, 0.f, 0.f, 0.f};
#pragma unroll
    for (int rb = 0; rb < 4; ++rb)
#pragma unroll
        for (int cb = 0; cb < 4; ++cb) acc[rb][cb] = z;

    float vreg[4], qreg[4];
#pragma unroll
    for (int cb = 0; cb < 4; ++cb) {
        vreg[cb] = v[w * 64 + cb * 16 + c];
        qreg[cb] = qs[b * H + w * 64 + cb * 16 + c];
    }

    // prologue: stage tile 0
    LOADA_G(0)
    STAGE_B(0, 0)
    WRITEA(0)
    __syncthreads();

#pragma unroll
    for (int st = 0; st < 16; ++st) {
        const int pb = st & 1;
        if (st < 15) {
            LOADA_G(st + 1)
            STAGE_B(st + 1, pb ^ 1)
        }
        {
            const char* ab_ = (const char*)&As[pb][0] + c * 80 + g * 16;
            const char* bb_ = (const char*)&Bs[pb][w * 4096] + l * 16;
            const short8 af0 = *(const short8*)(ab_);
            const short8 af1 = *(const short8*)(ab_ + 16 * 80);
            const short8 af2 = *(const short8*)(ab_ + 32 * 80);
            const short8 af3 = *(const short8*)(ab_ + 48 * 80);
#pragma unroll
            for (int cb = 0; cb < 4; ++cb) {
                const short8 bf = *(const short8*)(bb_ + cb * 1024);
                acc[0][cb] = __builtin_amdgcn_mfma_f32_16x16x32_bf16(af0, bf, acc[0][cb], 0, 0, 0);
                acc[1][cb] = __builtin_amdgcn_mfma_f32_16x16x32_bf16(af1, bf, acc[1][cb], 0, 0, 0);
                acc[2][cb] = __builtin_amdgcn_mfma_f32_16x16x32_bf16(af2, bf, acc[2][cb], 0, 0, 0);
                acc[3][cb] = __builtin_amdgcn_mfma_f32_16x16x32_bf16(af3, bf, acc[3][cb], 0, 0, 0);
            }
        }
        if (st < 15) WRITEA(pb ^ 1)
        __syncthreads();
    }

    // epilogue: p[row] = sum_col v[col] * tanh(escore + qs[col])
    float part[4][4];
#pragma unroll
    for (int rb = 0; rb < 4; ++rb)
#pragma unroll
        for (int r = 0; r < 4; ++r) part[rb][r] = 0.f;

#pragma unroll
    for (int cb = 0; cb < 4; ++cb)
#pragma unroll
        for (int rb = 0; rb < 4; ++rb)
#pragma unroll
            for (int r = 0; r < 4; ++r)
                part[rb][r] += vreg[cb] * ftanh(acc[rb][cb][r] + qreg[cb]);
#pragma unroll
    for (int m = 1; m < 16; m <<= 1)
#pragma unroll
        for (int rb = 0; rb < 4; ++rb)
#pragma unroll
            for (int r = 0; r < 4; ++r)
                part[rb][r] += __shfl_xor(part[rb][r], m);
    if (c == 0) {
#pragma unroll
        for (int rb = 0; rb < 4; ++rb)
#pragma unroll
            for (int r = 0; r < 4; ++r)
                red[w][rb * 16 + g * 4 + r] = part[rb][r];
    }
    __syncthreads();
    if (t < BMT)
        scores[b * S + s0 + t] = red[0][t] + red[1][t] + red[2][t] + red[3][t] +
                                 red[4][t] + red[5][t] + red[6][t] + red[7][t];
#undef STAGE_B
#undef LOADA_G
#undef WRITEA
}

// ---------------- kernel 3: masked softmax over S, write attn ----------------
__global__ __launch_bounds__(256) void softmax_kernel(const float* __restrict__ scores,
                                                      const int* __restrict__ lens,
                                                      float* __restrict__ attn) {
    const int b = blockIdx.x, t = threadIdx.x;
    const int len = lens[b];
    const int wave = t >> 6, lane = t & 63;
    __shared__ float red[4];

    float vals[8];
    float m = -INFINITY;
#pragma unroll
    for (int i = 0; i < 8; ++i) {
        const int s = i * 256 + t;
        vals[i] = (s < len) ? scores[b * S + s] : -INFINITY;
        m = fmaxf(m, vals[i]);
    }
#pragma unroll
    for (int off = 32; off > 0; off >>= 1) m = fmaxf(m, __shfl_down(m, off));
    if (lane == 0) red[wave] = m;
    __syncthreads();
    m = fmaxf(fmaxf(red[0], red[1]), fmaxf(red[2], red[3]));
    __syncthreads();

    float e[8];
    float sum = 0.f;
#pragma unroll
    for (int i = 0; i < 8; ++i) {
        const int s = i * 256 + t;
        e[i] = (s < len) ? expf(vals[i] - m) : 0.f;
        sum += e[i];
    }
#pragma unroll
    for (int off = 32; off > 0; off >>= 1) sum += __shfl_down(sum, off);
    if (lane == 0) red[wave] = sum;
    __syncthreads();
    const float inv = 1.f / (red[0] + red[1] + red[2] + red[3]);
#pragma unroll
    for (int i = 0; i < 8; ++i) attn[b * S + i * 256 + t] = e[i] * inv;
}

// -------- kernel 4a: partial context sums over s-chunks (masked skipped) --------
__global__ __launch_bounds__(256) void ctx_partial_kernel(const float* __restrict__ enc,
                                                          const float* __restrict__ attn,
                                                          const int* __restrict__ lens,
                                                          float* __restrict__ pc) {
    const int b = blockIdx.x >> 5, c = blockIdx.x & 31;
    const int len = lens[b];
    const int sbase = c * CHUNK;
    if (sbase >= len) return;
    const int ns = min(CHUNK, len - sbase);
    const int t = threadIdx.x;

    __shared__ float alds[CHUNK];
    if (t < CHUNK) alds[t] = (t < ns) ? attn[b * S + sbase + t] : 0.f;
    __syncthreads();

    const float2* e2 = (const float2*)(enc + (size_t)(b * S + sbase) * H);
    float2 acc = make_float2(0.f, 0.f);
    for (int s = 0; s < ns; ++s) {
        const float a = alds[s];
        const float2 e = e2[s * 256 + t];
        acc.x = fmaf(a, e.x, acc.x);
        acc.y = fmaf(a, e.y, acc.y);
    }
    ((float2*)(pc + (size_t)(b * NCHUNK + c) * H))[t] = acc;
}

// ------ kernel 4b: context reduce + w_out = tanh([ctx, q] @ W_out) ------
__global__ __launch_bounds__(512) void out_kernel(const float* __restrict__ pc,
                                                  const float* __restrict__ query,
                                                  const float* __restrict__ W_out,
                                                  const int* __restrict__ lens,
                                                  float* __restrict__ wout) {
    const int b = blockIdx.x, k = threadIdx.x;
    const int len = lens[b];
    const int nch = (len + CHUNK - 1) / CHUNK;
    __shared__ float cat[2 * H];
    float ctx = 0.f;
    for (int c = 0; c < nch; ++c) ctx += pc[(size_t)(b * NCHUNK + c) * H + k];
    cat[k] = ctx;
    cat[H + k] = query[b * H + k];
    __syncthreads();
    float acc = 0.f;
#pragma unroll 8
    for (int c = 0; c < 2 * H; ++c) acc = fmaf(cat[c], W_out[c * H + k], acc);
    wout[b * H + k] = tanhf(acc);
}

extern "C" void kernel_launch(void* const* d_in, const int* in_sizes, int n_in,
                              void* d_out, int out_size, void* d_ws, size_t ws_size,
                              hipStream_t stream) {
    const float* query = (const float*)d_in[0];
    const float* enc   = (const float*)d_in[1];
    const int*   lens  = (const int*)d_in[2];
    const float* W_h   = (const float*)d_in[3];
    const float* W_s   = (const float*)d_in[4];
    const float* v     = (const float*)d_in[5];
    const float* W_out = (const float*)d_in[6];

    float* out  = (float*)d_out;
    float* wout = out;          // B*H
    float* attn = out + B * H;  // B*S

    float* ws     = (float*)d_ws;
    float* qs     = ws + QS_OFF;
    float* scores = ws + SC_OFF;
    float* pc     = ws + PC_OFF;
    short* Wt     = (short*)(ws + PC_OFF);   // aliases pc: Wt used in scores (before pc written)

    qs_kernel<<<B, H, 0, stream>>>(query, W_s, qs);
    wt_prep<<<1024, 256, 0, stream>>>(W_h, Wt);
    scores_mfma_kernel<<<B * (S / BMT), 512, 0, stream>>>(enc, Wt, v, lens, qs, scores);
    softmax_kernel<<<B, 256, 0, stream>>>(scores, lens, attn);
    ctx_partial_kernel<<<B * NCHUNK, 256, 0, stream>>>(enc, attn, lens, pc);
    out_kernel<<<B, H, 0, stream>>>(pc, query, W_out, lens, wout);
}